// Round 12
// baseline (120.519 us; speedup 1.0000x reference)
//
#include <hip/hip_runtime.h>
#include <hip/hip_bf16.h>

typedef __hip_bfloat16 bf16;
typedef __attribute__((ext_vector_type(8))) short short8;
typedef __attribute__((ext_vector_type(8))) __bf16 bf16x8;
typedef __attribute__((ext_vector_type(2))) float f32x2;
typedef __attribute__((ext_vector_type(4))) float f32x4;
typedef __attribute__((ext_vector_type(16))) float f32x16;
typedef __attribute__((ext_vector_type(4))) unsigned int u32x4;
typedef __attribute__((ext_vector_type(2))) unsigned int u32x2;

// 16x16x32: C/D col = lane&15, row = (lane>>4)*4 + reg  [m89/m91]
#define MFMA16(a, b, c)                                                        \
  __builtin_amdgcn_mfma_f32_16x16x32_bf16(__builtin_bit_cast(bf16x8, (a)),     \
                                          __builtin_bit_cast(bf16x8, (b)),     \
                                          (c), 0, 0, 0)
// 32x32x16: C/D col = lane&31, row = (reg&3)+8*(reg>>2)+4*(lane>>5) [m74/m101]
#define MFMA32(a, b, c)                                                        \
  __builtin_amdgcn_mfma_f32_32x32x16_bf16(__builtin_bit_cast(bf16x8, (a)),     \
                                          __builtin_bit_cast(bf16x8, (b)),     \
                                          (c), 0, 0, 0)

// async global->LDS, 16B/lane; LDS dest = wave-uniform base + lane*16 [m97]
#define GLD16(gsrc, ldst)                                                      \
  __builtin_amdgcn_global_load_lds(                                            \
      (const __attribute__((address_space(1))) void*)(gsrc),                   \
      (__attribute__((address_space(3))) void*)(ldst), 16, 0, 0)

// ONE instruction: packs 2 f32 -> 2 bf16 in a u32 (RNE).
__device__ inline unsigned pk2(float lo, float hi) {
  unsigned r;
  asm("v_cvt_pk_bf16_f32 %0, %1, %2" : "=v"(r) : "v"(lo), "v"(hi));
  return r;
}
// packed fp32 fma: {a,b} * {m,m} + {c,c} in one VOP3P instruction
__device__ inline f32x2 pkfma(f32x2 s, f32x2 m, f32x2 a) {
  f32x2 r;
  asm("v_pk_fma_f32 %0, %1, %2, %3" : "=v"(r) : "v"(s), "v"(m), "v"(a));
  return r;
}
__device__ inline short f2bfs(float f) {
  return __builtin_bit_cast(short, __float2bfloat16(f));
}

template <typename T> __device__ inline short8 ld8bf(const T* p);
template <> __device__ inline short8 ld8bf<bf16>(const bf16* p) {
  return *(const short8*)p;
}
template <> __device__ inline short8 ld8bf<float>(const float* p) {
  f32x4 a = *(const f32x4*)p;
  f32x4 b = *(const f32x4*)(p + 4);
  u32x4 r;
  r[0] = pk2(a[0], a[1]);
  r[1] = pk2(a[2], a[3]);
  r[2] = pk2(b[0], b[1]);
  r[3] = pk2(b[2], b[3]);
  return __builtin_bit_cast(short8, r);
}

template <typename OT> __device__ inline void st1(OT* p, float v);
template <> __device__ inline void st1<bf16>(bf16* p, float v) {
  *p = __float2bfloat16(v);
}
template <> __device__ inline void st1<float>(float* p, float v) { *p = v; }

__device__ inline unsigned int funnel16(unsigned int hi, unsigned int lo) {
  return (unsigned int)(((((unsigned long long)hi) << 32) | lo) >> 16);
}
// u[j] = v[(j + r) & 7] — rotate 8 shorts left by r, all-static indexing.
__device__ inline short8 rotl8(short8 v, int r) {
  u32x4 W = __builtin_bit_cast(u32x4, v);
  u32x4 T, U, F;
  int wr = r >> 1;
  T[0] = (wr & 1) ? W[1] : W[0];
  T[1] = (wr & 1) ? W[2] : W[1];
  T[2] = (wr & 1) ? W[3] : W[2];
  T[3] = (wr & 1) ? W[0] : W[3];
  U[0] = (wr & 2) ? T[2] : T[0];
  U[1] = (wr & 2) ? T[3] : T[1];
  U[2] = (wr & 2) ? T[0] : T[2];
  U[3] = (wr & 2) ? T[1] : T[3];
  F[0] = (r & 1) ? funnel16(U[1], U[0]) : U[0];
  F[1] = (r & 1) ? funnel16(U[2], U[1]) : U[1];
  F[2] = (r & 1) ? funnel16(U[3], U[2]) : U[2];
  F[3] = (r & 1) ? funnel16(U[0], U[3]) : U[3];
  return __builtin_bit_cast(short8, F);
}

// ---------------------------------------------------------------------------
// cvt3: fp32 -> bf16 for three arrays (x, w_qkv, w_out), 8 elems/thread.
// ---------------------------------------------------------------------------
__global__ __launch_bounds__(256) void cvt3(
    const float* __restrict__ s0, bf16* __restrict__ d0, int n0,
    const float* __restrict__ s1, bf16* __restrict__ d1, int n1,
    const float* __restrict__ s2, bf16* __restrict__ d2, int n2) {
  int i = (blockIdx.x * 256 + threadIdx.x) * 8;
  if (i < n0) {
    *(short8*)&d0[i] = ld8bf(s0 + i);
  } else if ((i -= n0) < n1) {
    *(short8*)&d1[i] = ld8bf(s1 + i);
  } else if ((i -= n1) < n2) {
    *(short8*)&d2[i] = ld8bf(s2 + i);
  }
}

// ---------------------------------------------------------------------------
// FAST GEMM (m97 structure): all-bf16, global_load_lds width-16.
// Tile 128 x BN (BN = 128 or 64), BK=64, 256 thr = 2x2 waves.
// ---------------------------------------------------------------------------
template <int BN, typename OT>
__global__ __launch_bounds__(256, 2) void gemm_lds_bias(
    const bf16* __restrict__ A, const bf16* __restrict__ B,
    const float* __restrict__ bias, OT* __restrict__ C, int M, int N, int K) {
  __shared__ bf16 As[128][64];
  __shared__ bf16 Bs[BN][64];

  const int tid = threadIdx.x;
  const int w = tid >> 6, l = tid & 63;
  const int wr = w >> 1, wc = w & 1;
  const int m0 = blockIdx.y * 128, n0 = blockIdx.x * BN;
  const int JN = BN / 64;
  const int WCOL = BN / 2;

  f32x4 acc[4][2 * JN] = {};

  const int srow = l >> 3;
  const int scol = (l & 7) * 8;

  for (int kt = 0; kt < K; kt += 64) {
#pragma unroll
    for (int j = 0; j < 4; ++j) {
      int chunk = w * 4 + j;
      int row = chunk * 8 + srow;
      GLD16(A + (size_t)(m0 + row) * K + kt + scol, &As[0][0] + chunk * 512);
    }
#pragma unroll
    for (int j = 0; j < BN / 32; ++j) {
      int chunk = w * (BN / 32) + j;
      int row = chunk * 8 + srow;
      GLD16(B + (size_t)(n0 + row) * K + kt + scol, &Bs[0][0] + chunk * 512);
    }
    __syncthreads();

#pragma unroll
    for (int kk = 0; kk < 2; ++kk) {
      short8 af[4], bfv[2 * JN];
#pragma unroll
      for (int i = 0; i < 4; ++i)
        af[i] = *(const short8*)&As[wr * 64 + i * 16 + (l & 15)]
                                  [kk * 32 + (l >> 4) * 8];
#pragma unroll
      for (int jn = 0; jn < 2 * JN; ++jn)
        bfv[jn] = *(const short8*)&Bs[wc * WCOL + jn * 16 + (l & 15)]
                                    [kk * 32 + (l >> 4) * 8];
#pragma unroll
      for (int i = 0; i < 4; ++i)
#pragma unroll
        for (int jn = 0; jn < 2 * JN; ++jn)
          acc[i][jn] = MFMA16(af[i], bfv[jn], acc[i][jn]);
    }
    __syncthreads();
  }

#pragma unroll
  for (int i = 0; i < 4; ++i) {
    int rbase = m0 + wr * 64 + i * 16 + (l >> 4) * 4;
#pragma unroll
    for (int jn = 0; jn < 2 * JN; ++jn) {
      int col = n0 + wc * WCOL + jn * 16 + (l & 15);
      float bv = bias[col];
#pragma unroll
      for (int r = 0; r < 4; ++r)
        st1(&C[(size_t)(rbase + r) * N + col], acc[i][jn][r] + bv);
    }
  }
}

// ---------------------------------------------------------------------------
// FALLBACK GEMM (reg-staged, fp32/bf16 template) — used if ws too small.
// ---------------------------------------------------------------------------
template <typename AT, typename OT>
__global__ __launch_bounds__(256, 2) void gemm_bt_bias(
    const AT* __restrict__ A, const float* __restrict__ B,
    const float* __restrict__ bias, OT* __restrict__ C, int M, int N, int K) {
  __shared__ bf16 As[128][64];
  __shared__ bf16 Bs[128][64];

  const int tid = threadIdx.x;
  const int w = tid >> 6, l = tid & 63;
  const int wr = w >> 1, wc = w & 1;
  const int m0 = blockIdx.y * 128, n0 = blockIdx.x * 128;

  f32x4 acc[4][4] = {};

  const int srow = tid >> 3;
  const int scol = (tid & 7) * 8;

  for (int kt = 0; kt < K; kt += 64) {
    short8 aReg[4], bReg[4];
#pragma unroll
    for (int p = 0; p < 4; ++p) {
      int row = p * 32 + srow;
      aReg[p] = ld8bf(A + (size_t)(m0 + row) * K + kt + scol);
      bReg[p] = ld8bf(B + (size_t)(n0 + row) * K + kt + scol);
    }
    __syncthreads();
#pragma unroll
    for (int p = 0; p < 4; ++p) {
      int row = p * 32 + srow;
      *(short8*)&As[row][scol] = aReg[p];
      *(short8*)&Bs[row][scol] = bReg[p];
    }
    __syncthreads();

#pragma unroll
    for (int kk = 0; kk < 2; ++kk) {
      short8 af[4], bfv[4];
#pragma unroll
      for (int i = 0; i < 4; ++i) {
        af[i]  = *(const short8*)&As[wr * 64 + i * 16 + (l & 15)]
                                   [kk * 32 + (l >> 4) * 8];
        bfv[i] = *(const short8*)&Bs[wc * 64 + i * 16 + (l & 15)]
                                   [kk * 32 + (l >> 4) * 8];
      }
#pragma unroll
      for (int i = 0; i < 4; ++i)
#pragma unroll
        for (int jn = 0; jn < 4; ++jn)
          acc[i][jn] = MFMA16(af[i], bfv[jn], acc[i][jn]);
    }
  }

#pragma unroll
  for (int i = 0; i < 4; ++i) {
    int rbase = m0 + wr * 64 + i * 16 + (l >> 4) * 4;
#pragma unroll
    for (int jn = 0; jn < 4; ++jn) {
      int col = n0 + wc * 64 + jn * 16 + (l & 15);
      float bv = bias[col];
#pragma unroll
      for (int r = 0; r < 4; ++r)
        st1(&C[(size_t)(rbase + r) * N + col], acc[i][jn][r] + bv);
    }
  }
}

// ---------------------------------------------------------------------------
// Flash attention, swapped-operand 32x32 MFMA, KVBLK=128
// + permlane32_swap P-exchange + cvt_pk packing
// + MFMA-accumulated l_i (ones-fragment) + pk_fma exp-prep.
// ---------------------------------------------------------------------------
__global__ __launch_bounds__(256, 2) void attn_fwd(
    const bf16* __restrict__ qkv, bf16* __restrict__ attended) {
  const int S = 2048, D3 = 3072, D = 1024;
  // bijective XCD swizzle (512 = 8 x 64): each XCD owns 4 bh values entirely.
  const int flat = blockIdx.y * 16 + blockIdx.x;
  const int n = (flat & 7) * 64 + (flat >> 3);
  const int qt = n & 15, bh = n >> 4;
  const int b = bh >> 4, h = bh & 15;
  const int tid = threadIdx.x, w = tid >> 6, l = tid & 63;
  const int lo5 = l & 31, hi = l >> 5;

  __shared__ bf16 Klds[128][72];  // K[kv][e], row stride 144B
  __shared__ bf16 Vt[64][136];    // V^T[e][kv], row stride 272B

  const int q0w = qt * 128 + w * 32;

  short8 qf[4];
  {
    size_t qrow = (size_t)(b * S + q0w + lo5) * D3 + h * 64;
#pragma unroll
    for (int ks = 0; ks < 4; ++ks)
      qf[ks] = *(const short8*)&qkv[qrow + ks * 16 + hi * 8];
  }

  // all-ones bf16 A-fragment for the l_i-sum MFMA
  const u32x4 onesw = {0x3F803F80u, 0x3F803F80u, 0x3F803F80u, 0x3F803F80u};
  const short8 ones = __builtin_bit_cast(short8, onesw);

  float m_raw = -1e30f;
  f32x16 o0 = {}, o1 = {}, oL = {};

  const float Cs = 0.125f * 1.44269504088896340736f;  // hd^-0.5 * log2(e)

  const int srow = tid >> 2;
  const int scq = tid & 3;
  const size_t gb0 = (size_t)(b * S + srow) * D3 + h * 64 + scq * 16;
  const size_t HSTEP = (size_t)64 * D3;

  short8 k0, k1, k2, k3, v0, v1, v2, v3;
  {
    const bf16* g = qkv + gb0;
    k0 = *(const short8*)&g[1024];
    k1 = *(const short8*)&g[1024 + 8];
    v0 = *(const short8*)&g[2048];
    v1 = *(const short8*)&g[2048 + 8];
    const bf16* g2 = g + HSTEP;
    k2 = *(const short8*)&g2[1024];
    k3 = *(const short8*)&g2[1024 + 8];
    v2 = *(const short8*)&g2[2048];
    v3 = *(const short8*)&g2[2048 + 8];
  }

#define PACKP(G, SV)                                                           \
  {                                                                            \
    _Pragma("unroll") for (int tq = 0; tq < 4; ++tq) {                         \
      po[G][tq][0] = pk2((SV)[4 * tq], (SV)[4 * tq + 1]);                      \
      po[G][tq][1] = pk2((SV)[4 * tq + 2], (SV)[4 * tq + 3]);                  \
    }                                                                          \
  }
// packed exp-prep: SV[r] = exp2(SV[r]*Cs - pc) over 16 lanes-local values
#define EXPP(SV)                                                               \
  {                                                                            \
    _Pragma("unroll") for (int r2 = 0; r2 < 8; ++r2) {                         \
      f32x2 p;                                                                 \
      p[0] = (SV)[2 * r2];                                                     \
      p[1] = (SV)[2 * r2 + 1];                                                 \
      p = pkfma(p, csc, npc);                                                  \
      (SV)[2 * r2] = __builtin_amdgcn_exp2f(p[0]);                             \
      (SV)[2 * r2 + 1] = __builtin_amdgcn_exp2f(p[1]);                         \
    }                                                                          \
  }

  for (int t = 0; t < 16; ++t) {
    __syncthreads();  // WAR
    *(short8*)&Klds[srow][scq * 16] = k0;
    *(short8*)&Klds[srow][scq * 16 + 8] = k1;
    *(short8*)&Klds[64 + srow][scq * 16] = k2;
    *(short8*)&Klds[64 + srow][scq * 16 + 8] = k3;
#pragma unroll
    for (int g = 0; g < 2; ++g) {
      int sI = scq * 2 + g;
      short8 ua = rotl8(g ? v1 : v0, sI);
      short8 ub = rotl8(g ? v3 : v2, sI);
#pragma unroll
      for (int j = 0; j < 8; ++j) {
        int jj = (j + sI) & 7;
        *(short*)&Vt[sI * 8 + jj][srow] = (short)ua[j];
        *(short*)&Vt[sI * 8 + jj][64 + srow] = (short)ub[j];
      }
    }
    __syncthreads();

    if (t + 1 < 16) {  // prefetch next K
      const bf16* g = qkv + gb0 + (size_t)(t + 1) * 2 * HSTEP;
      k0 = *(const short8*)&g[1024];
      k1 = *(const short8*)&g[1024 + 8];
      k2 = *(const short8*)&g[HSTEP + 1024];
      k3 = *(const short8*)&g[HSTEP + 1024 + 8];
    }

    // S^T = K @ Q^T
    f32x16 s0 = {}, s1 = {}, s2 = {}, s3 = {};
    __builtin_amdgcn_s_setprio(1);
#pragma unroll
    for (int ks = 0; ks < 4; ++ks) {
      short8 km0 = *(const short8*)&Klds[lo5][ks * 16 + hi * 8];
      short8 km1 = *(const short8*)&Klds[32 + lo5][ks * 16 + hi * 8];
      short8 km2 = *(const short8*)&Klds[64 + lo5][ks * 16 + hi * 8];
      short8 km3 = *(const short8*)&Klds[96 + lo5][ks * 16 + hi * 8];
      s0 = MFMA32(km0, qf[ks], s0);
      s1 = MFMA32(km1, qf[ks], s1);
      s2 = MFMA32(km2, qf[ks], s2);
      s3 = MFMA32(km3, qf[ks], s3);
    }
    __builtin_amdgcn_s_setprio(0);

    if (t + 1 < 16) {  // prefetch next V
      const bf16* g = qkv + gb0 + (size_t)(t + 1) * 2 * HSTEP;
      v0 = *(const short8*)&g[2048];
      v1 = *(const short8*)&g[2048 + 8];
      v2 = *(const short8*)&g[HSTEP + 2048];
      v3 = *(const short8*)&g[HSTEP + 2048 + 8];
    }

    // max over 128 kv (max3-fused trees)
    f32x16 tm;
#pragma unroll
    for (int r = 0; r < 16; ++r)
      tm[r] = fmaxf(fmaxf(fmaxf(s0[r], s1[r]), s2[r]), s3[r]);
    float a0 = fmaxf(fmaxf(tm[0], tm[1]), tm[2]);
    float a1 = fmaxf(fmaxf(tm[3], tm[4]), tm[5]);
    float a2 = fmaxf(fmaxf(tm[6], tm[7]), tm[8]);
    float a3 = fmaxf(fmaxf(tm[9], tm[10]), tm[11]);
    float a4 = fmaxf(fmaxf(tm[12], tm[13]), tm[14]);
    float b0v = fmaxf(fmaxf(a0, a1), a2);
    float b1v = fmaxf(fmaxf(a3, a4), tm[15]);
    float mx = fmaxf(b0v, b1v);
    mx = fmaxf(mx, __shfl_xor(mx, 32));

    bool deferred = __all((mx - m_raw) * Cs <= 8.0f);
    if (!deferred) {
      float mn = fmaxf(m_raw, mx);
      float alpha = __builtin_amdgcn_exp2f((m_raw - mn) * Cs);
      m_raw = mn;
      o0 *= alpha;
      o1 *= alpha;
      oL *= alpha;
    }
    float pc = m_raw * Cs;
    f32x2 csc, npc;
    csc[0] = Cs; csc[1] = Cs;
    npc[0] = -pc; npc[1] = -pc;

    EXPP(s0) EXPP(s1) EXPP(s2) EXPP(s3)

    // pack P quads (po[g][tq][hf]: kv = 32g + 8tq + 4hi + {0..3})
    unsigned po[4][4][2];
    PACKP(0, s0) PACKP(1, s1) PACKP(2, s2) PACKP(3, s3)

    // O^T += V^T @ P^T; l_i rides along as ones-fragment MFMA
    __builtin_amdgcn_s_setprio(1);
#pragma unroll
    for (int ks2 = 0; ks2 < 8; ++ks2) {
      const int g = ks2 >> 1, p = ks2 & 1;
      u32x2 ra = __builtin_amdgcn_permlane32_swap(po[g][2 * p][0],
                                                  po[g][2 * p + 1][0],
                                                  false, false);
      u32x2 rb = __builtin_amdgcn_permlane32_swap(po[g][2 * p][1],
                                                  po[g][2 * p + 1][1],
                                                  false, false);
      u32x4 fw;
      fw[0] = ra[0];
      fw[1] = rb[0];
      fw[2] = ra[1];
      fw[3] = rb[1];
      short8 pf = __builtin_bit_cast(short8, fw);
      short8 va0 = *(const short8*)&Vt[lo5][ks2 * 16 + hi * 8];
      short8 va1 = *(const short8*)&Vt[32 + lo5][ks2 * 16 + hi * 8];
      o0 = MFMA32(va0, pf, o0);
      o1 = MFMA32(va1, pf, o1);
      oL = MFMA32(ones, pf, oL);
    }
    __builtin_amdgcn_s_setprio(0);
  }

  float inv = 1.0f / oL[0];
  size_t orow = (size_t)(b * S + q0w + lo5) * D + h * 64;
#pragma unroll
  for (int t = 0; t < 4; ++t) {
    u32x2 w0, w1;
    w0[0] = pk2(o0[4 * t] * inv, o0[4 * t + 1] * inv);
    w0[1] = pk2(o0[4 * t + 2] * inv, o0[4 * t + 3] * inv);
    w1[0] = pk2(o1[4 * t] * inv, o1[4 * t + 1] * inv);
    w1[1] = pk2(o1[4 * t + 2] * inv, o1[4 * t + 3] * inv);
    *(u32x2*)&attended[orow + 8 * t + 4 * hi] = w0;
    *(u32x2*)&attended[orow + 32 + 8 * t + 4 * hi] = w1;
  }
}

// ---------------------------------------------------------------------------
extern "C" void kernel_launch(void* const* d_in, const int* in_sizes, int n_in,
                              void* d_out, int out_size, void* d_ws,
                              size_t ws_size, hipStream_t stream) {
  const float* x     = (const float*)d_in[0];   // [2,2048,1024] fp32
  const float* w_qkv = (const float*)d_in[1];   // [3072,1024]   fp32
  const float* b_qkv = (const float*)d_in[2];   // [3072]        fp32
  const float* w_out = (const float*)d_in[3];   // [1024,1024]   fp32
  const float* b_out = (const float*)d_in[4];   // [1024]        fp32
  float* out = (float*)d_out;                   // [2,2048,1024] fp32

  const int BS = 4096;   // B*S
  const int D = 1024, D3 = 3072;
  const int NX = BS * D, NWQ = D3 * D, NWO = D * D;

  bf16* qkv = (bf16*)d_ws;                       // [4096][3072] 25.2 MB
  bf16* att = qkv + (size_t)BS * D3;             // [4096][1024]  8.4 MB

  const size_t NEED = ((size_t)BS * D3 + (size_t)BS * D + (size_t)D3 * D +
                       (size_t)D * D) * sizeof(bf16);

  if (ws_size >= NEED) {
    bf16* xb  = att;                             // overlaid with att
    bf16* wqb = xb + (size_t)NX;
    bf16* wob = wqb + (size_t)NWQ;

    int ncvt = (NX + NWQ + NWO) / 8;
    cvt3<<<(ncvt + 255) / 256, 256, 0, stream>>>(x, xb, NX, w_qkv, wqb, NWQ,
                                                 w_out, wob, NWO);
    gemm_lds_bias<128, bf16><<<dim3(D3 / 128, BS / 128), 256, 0, stream>>>(
        xb, wqb, b_qkv, qkv, BS, D3, D);
    attn_fwd<<<dim3(16, 32), 256, 0, stream>>>(qkv, att);  // clobbers xb/wqb
    gemm_lds_bias<64, float><<<dim3(D / 64, BS / 128), 256, 0, stream>>>(
        att, wob, b_out, out, BS, D, D);
  } else {
    gemm_bt_bias<float, bf16><<<dim3(D3 / 128, BS / 128), 256, 0, stream>>>(
        x, w_qkv, b_qkv, qkv, BS, D3, D);
    attn_fwd<<<dim3(16, 32), 256, 0, stream>>>(qkv, att);
    gemm_bt_bias<bf16, float><<<dim3(D / 128, BS / 128), 256, 0, stream>>>(
        att, w_out, b_out, out, BS, D, D);
  }
}